// Round 5
// baseline (359.395 us; speedup 1.0000x reference)
//
#include <hip/hip_runtime.h>
#include <math.h>

// Problem constants (reference: B=16, C=256, H=80, W=80, K=3, ALPHA=0.1, EPS=1e-7)
#define L_LEN 6400        // H*W
#define NROWS 4096        // B*C
#define C_CH 256
#define CHUNK 1280        // 64 lanes * 20 elements
#define VPT 20
#define EPS_F 1e-7f
#define LOG2_DECAY_F -0.15200309f   // log2(0.9)

typedef float v4f __attribute__((ext_vector_type(4)));

// One wave's view of one chunk: 20 contiguous floats/lane + conv edge neighbors.
struct Chunk {
    v4f v[5];
    float xl, xr;
};

#define XV(d, j) ((j) == 0 ? (d).v[0].x : (j) == 1 ? (d).v[0].y : (j) == 2 ? (d).v[0].z : (j) == 3 ? (d).v[0].w : \
                  (j) == 4 ? (d).v[1].x : (j) == 5 ? (d).v[1].y : (j) == 6 ? (d).v[1].z : (j) == 7 ? (d).v[1].w : \
                  (j) == 8 ? (d).v[2].x : (j) == 9 ? (d).v[2].y : (j) ==10 ? (d).v[2].z : (j) ==11 ? (d).v[2].w : \
                  (j) ==12 ? (d).v[3].x : (j) ==13 ? (d).v[3].y : (j) ==14 ? (d).v[3].z : (j) ==15 ? (d).v[3].w : \
                  (j) ==16 ? (d).v[4].x : (j) ==17 ? (d).v[4].y : (j) ==18 ? (d).v[4].z : (d).v[4].w)

__device__ __forceinline__ void load_chunk(const float* __restrict__ x, long ro, int c, int lane, Chunk& d) {
    const int pos = c * CHUNK + lane * VPT;
    const v4f* p4 = (const v4f*)(x + ro + pos);
#pragma unroll
    for (int i = 0; i < 5; ++i) d.v[i] = p4[i];
    d.xl = (pos == 0)            ? 0.f : x[ro + pos - 1];     // only lane0/chunk0 masked
    d.xr = (pos + VPT == L_LEN)  ? 0.f : x[ro + pos + VPT];   // only lane63/chunk4 masked
}

template <bool FIRST>
__device__ __forceinline__ void compute_chunk(
    const Chunk& d, int c, int lane, float g, float& Rp,
    float w0, float w1, float w2, float bias,
    float* __restrict__ out, long ro)
{
    const int pos = c * CHUNK + lane * VPT;
    v4f* go = (v4f*)(out + ro + pos);

    if (FIRST) {
        // local weighted dot: p = sum_j x[j] * 0.1*0.9^j ; lane scale g = 0.9^(20*lane)
        float p = 0.f, w = 0.1f;
#pragma unroll
        for (int j = 0; j < VPT; ++j) { p = fmaf(XV(d, j), w, p); w *= 0.9f; }
        float s = g * p;

        // wave-only inclusive scan (no LDS, no barriers)
        float inc = s;
#pragma unroll
        for (int off = 1; off < 64; off <<= 1) {
            float n = __shfl_up(inc, off, 64);
            if (lane >= off) inc += n;
        }
        const float excl  = inc - s;
        const float total = __shfl(inc, 63);

        float pj = 0.f;
        w = 0.1f;
        v4f ov;
#pragma unroll
        for (int j = 0; j < VPT; ++j) {
            pj = fmaf(XV(d, j), w, pj);
            float cum = fmaf(g, pj, excl);                       // row prefix at this element
            float cd  = fmaf(-9.f * g, w, 1.0f) + EPS_F;         // 1 - 0.9^(pos+1) + eps
            float ema = cum * __builtin_amdgcn_rcpf(cd);
            float prev = (j == 0)        ? d.xl : XV(d, j - 1);
            float nxt  = (j == VPT - 1)  ? d.xr : XV(d, j + 1);
            float o = ema + fmaf(w0, prev, fmaf(w1, XV(d, j), fmaf(w2, nxt, bias))) + XV(d, j);
            if ((j & 3) == 0) ov.x = o; else if ((j & 3) == 1) ov.y = o;
            else if ((j & 3) == 2) ov.z = o; else { ov.w = o; __builtin_nontemporal_store(ov, go + (j >> 2)); }
            w *= 0.9f;
        }
        // decay underflows to f32 zero beyond i~987: ema is constant for all later chunks
        Rp = total * __builtin_amdgcn_rcpf(1.0f + EPS_F);
    } else {
        v4f ov;
#pragma unroll
        for (int j = 0; j < VPT; ++j) {
            float prev = (j == 0)        ? d.xl : XV(d, j - 1);
            float nxt  = (j == VPT - 1)  ? d.xr : XV(d, j + 1);
            float o = Rp + fmaf(w0, prev, fmaf(w1, XV(d, j), fmaf(w2, nxt, bias))) + XV(d, j);
            if ((j & 3) == 0) ov.x = o; else if ((j & 3) == 1) ov.y = o;
            else if ((j & 3) == 2) ov.z = o; else { ov.w = o; __builtin_nontemporal_store(ov, go + (j >> 2)); }
        }
    }
}

// One wave per row, zero __syncthreads: waves run fully decoupled, loads for
// chunk c+1 stay in flight under chunk c's compute (no vmcnt(0) drains).
__global__ __launch_bounds__(256, 4) void ema_attn_kernel(
    const float* __restrict__ x,
    const float* __restrict__ conv_w,   // [C,1,3]
    const float* __restrict__ conv_b,   // [C]
    float* __restrict__ out)
{
    const int t    = threadIdx.x;
    const int lane = t & 63;
    const int wid  = t >> 6;
    const int row  = blockIdx.x * 4 + wid;
    const long ro  = (long)row * L_LEN;
    const int ch   = row & (C_CH - 1);

    const float w0   = conv_w[ch * 3 + 0];
    const float w1   = conv_w[ch * 3 + 1];
    const float w2   = conv_w[ch * 3 + 2];
    const float bias = conv_b[ch];

    // g = 0.9^(20*lane); underflows to 0 for lane >= ~50, matching reference f32 decay
    const float g = exp2f((float)(lane * VPT) * LOG2_DECAY_F);

    Chunk A, B;
    float R = 0.f;

    load_chunk(x, ro, 0, lane, A);
    load_chunk(x, ro, 1, lane, B);                 // in flight under chunk-0 compute
    compute_chunk<true >(A, 0, lane, g, R, w0, w1, w2, bias, out, ro);
    load_chunk(x, ro, 2, lane, A);                 // in flight under chunk-1 compute
    compute_chunk<false>(B, 1, lane, g, R, w0, w1, w2, bias, out, ro);
    load_chunk(x, ro, 3, lane, B);
    compute_chunk<false>(A, 2, lane, g, R, w0, w1, w2, bias, out, ro);
    load_chunk(x, ro, 4, lane, A);
    compute_chunk<false>(B, 3, lane, g, R, w0, w1, w2, bias, out, ro);
    compute_chunk<false>(A, 4, lane, g, R, w0, w1, w2, bias, out, ro);
}

extern "C" void kernel_launch(void* const* d_in, const int* in_sizes, int n_in,
                              void* d_out, int out_size, void* d_ws, size_t ws_size,
                              hipStream_t stream) {
    const float* x      = (const float*)d_in[0];
    const float* conv_w = (const float*)d_in[1];
    const float* conv_b = (const float*)d_in[2];
    float* out          = (float*)d_out;
    ema_attn_kernel<<<NROWS / 4, 256, 0, stream>>>(x, conv_w, conv_b, out);
}